// Round 11
// baseline (100.892 us; speedup 1.0000x reference)
//
#include <hip/hip_runtime.h>
#include <hip/hip_bf16.h>
#include <cstdint>
#include <cstddef>

#define B_  2
#define Q_  256
#define KL  2048
#define D_  256
#define H_  8
#define HD_ 32
#define CH_ 256

typedef _Float16 f16;
typedef __fp16 fp16x2 __attribute__((ext_vector_type(2)));
typedef _Float16 f16x8 __attribute__((ext_vector_type(8)));
typedef unsigned short ushortv4 __attribute__((ext_vector_type(4)));
typedef unsigned int uintv4 __attribute__((ext_vector_type(4)));
typedef float f32x4 __attribute__((ext_vector_type(4)));

union UH  { fp16x2 h; unsigned int u; };
union UH8 { f16x8 h; unsigned int u[4]; };

__device__ __forceinline__ unsigned int pkrtz(float a, float b) {
  UH r; r.h = __builtin_amdgcn_cvt_pkrtz(a, b); return r.u;
}
__device__ __forceinline__ unsigned short f16bits(float a) {
  return (unsigned short)(pkrtz(a, 0.f) & 0xffffu);
}
__device__ __forceinline__ unsigned int pk_fma(unsigned int a, unsigned int b,
                                               unsigned int c) {
  unsigned int d;
  asm("v_pk_fma_f16 %0, %1, %2, %3" : "=v"(d) : "v"(a), "v"(b), "v"(c));
  return d;
}
__device__ __forceinline__ unsigned int pk_max0(unsigned int a) {
  unsigned int d;
  asm("v_pk_max_f16 %0, %1, %2" : "=v"(d) : "v"(a), "v"(0u));
  return d;
}
__device__ __forceinline__ f16x8 pack8h(float4 a0, float4 a1) {
  UH8 u;
  u.u[0] = pkrtz(a0.x, a0.y);
  u.u[1] = pkrtz(a0.z, a0.w);
  u.u[2] = pkrtz(a1.x, a1.y);
  u.u[3] = pkrtz(a1.z, a1.w);
  return u.h;
}

// ---------- merged q + kv projection
// blocks [0,128): q-proj -> qp fp32 [b][q][c]
// blocks [128,2176): kv-proj -> kps swizzled f16 K, vt f16 [b][h][dd][k]
__global__ __launch_bounds__(256) void gemm_qkv(
    const float* __restrict__ ent, const float* __restrict__ Wq,
    const float* __restrict__ bq, float* __restrict__ qp,
    const float* __restrict__ img, const float* __restrict__ Wkv,
    const float* __restrict__ bkv, unsigned short* __restrict__ kps,
    unsigned short* __restrict__ vt) {
  int bid = blockIdx.x;
  int t = threadIdx.x, w = t >> 6, l = t & 63;
  int r = l & 15, g = l >> 4;
  if (bid < 128) {
    int nt = bid & 3, mt = bid >> 2;
    int m0 = mt * 16, n0 = nt * 64 + w * 16;
    const float* arow = ent + (size_t)(m0 + r) * D_;
    const float* wrow = Wq + (size_t)(n0 + r) * D_;
    f32x4 acc = {0.f, 0.f, 0.f, 0.f};
#pragma unroll
    for (int s = 0; s < 8; ++s) {
      int kb = s * 32 + g * 8;
      f16x8 af = pack8h(*(const float4*)(arow + kb), *(const float4*)(arow + kb + 4));
      f16x8 bf = pack8h(*(const float4*)(wrow + kb), *(const float4*)(wrow + kb + 4));
      acc = __builtin_amdgcn_mfma_f32_16x16x32_f16(af, bf, acc, 0, 0, 0);
    }
    int n = n0 + r;
    float bb = bq[n];
#pragma unroll
    for (int rr = 0; rr < 4; ++rr)
      qp[(size_t)(m0 + g * 4 + rr) * D_ + n] = acc[rr] + bb;
  } else {
    int bid2 = bid - 128;
    int nt = bid2 & 7, mt = (bid2 >> 3) & 127, b = bid2 >> 10;
    int m0 = mt * 16, n0 = nt * 64 + w * 16;
    const float* arow = img + (size_t)(b * KL + m0 + r) * D_;
    const float* wrow = Wkv + (size_t)(n0 + r) * D_;
    f32x4 acc = {0.f, 0.f, 0.f, 0.f};
#pragma unroll
    for (int s = 0; s < 8; ++s) {
      int kb = s * 32 + g * 8;
      f16x8 af = pack8h(*(const float4*)(arow + kb), *(const float4*)(arow + kb + 4));
      f16x8 bf = pack8h(*(const float4*)(wrow + kb), *(const float4*)(wrow + kb + 4));
      acc = __builtin_amdgcn_mfma_f32_16x16x32_f16(af, bf, acc, 0, 0, 0);
    }
    int n = n0 + r;
    float bb = bkv[n];
#pragma unroll
    for (int rr = 0; rr < 4; ++rr) acc[rr] += bb;
    if (n < 256) {
      int s2 = n >> 5, gg = (n >> 3) & 3, e = n & 7;
      size_t base = ((size_t)((b * 128 + mt) * 8 + s2) * 64 + gg * 16) * 8 + e;
#pragma unroll
      for (int rr = 0; rr < 4; ++rr)
        kps[base + (size_t)(g * 4 + rr) * 8] = f16bits(acc[rr]);
    } else {
      int c = n - 256, h = c >> 5, dd = c & 31;
      ushortv4 p;
#pragma unroll
      for (int rr = 0; rr < 4; ++rr) p[rr] = f16bits(acc[rr]);
      *(ushortv4*)(vt + ((size_t)(b * H_ + h) * HD_ + dd) * KL + m0 + g * 4) = p;
    }
  }
}

// ---------- logits = QK^T*scale + CPB (f16 MFMA), 2-q packed columns
// block = (b, 2 q-rows, 256 k), 256 threads (4 waves); wave -> 64 k.
// MFMA D cols 0-7 = q0 heads, 8-15 = q1 heads.
__global__ __launch_bounds__(256, 6) void logits_cpb(
    const float* __restrict__ qp, const unsigned short* __restrict__ kps,
    const float* __restrict__ rd, const float* __restrict__ W1,
    const float* __restrict__ b1, const float* __restrict__ W2,
    const float* __restrict__ b2, unsigned short* __restrict__ lgb,
    float* __restrict__ stats) {
  int gid = blockIdx.x;
  int kcg = gid & 7, qg = (gid >> 3) & 127, b = gid >> 10;
  int t = threadIdx.x;
  __shared__ unsigned int w1xs[128], w1ys[128], b1ps[128];  // half2-packed
  __shared__ unsigned short w2h[H_][264];
  __shared__ unsigned int qs[2][128];  // packed scaled q pairs per q-row
  __shared__ float b2s[H_];
  if (t < 128) {
    float4 wr = *(const float4*)(W1 + 4 * t);  // rows 2t, 2t+1 of W1[256][2]
    w1xs[t] = pkrtz(wr.x, wr.z);
    w1ys[t] = pkrtz(wr.y, wr.w);
    float2 bb = *(const float2*)(b1 + 2 * t);
    b1ps[t] = pkrtz(bb.x, bb.y);
  }
#pragma unroll
  for (int i = 0; i < 2; ++i) {  // all 8 heads (256 thr x 2 = 8h x 64 float4)
    int idx = t + i * 256;
    int h = idx >> 6, c0 = (idx & 63) * 4;
    float4 wv = *(const float4*)(W2 + h * CH_ + c0);
    w2h[h][c0 + 0] = f16bits(wv.x);
    w2h[h][c0 + 1] = f16bits(wv.y);
    w2h[h][c0 + 2] = f16bits(wv.z);
    w2h[h][c0 + 3] = f16bits(wv.w);
  }
  const float scale = 0.17677669529663687f;  // 1/sqrt(32)
  {
    int q = t >> 7, j = t & 127;  // 2q x 128 = 256
    float2 v = *(const float2*)(qp + ((size_t)(b * Q_ + qg * 2 + q) * D_) + 2 * j);
    qs[q][j] = pkrtz(v.x * scale, v.y * scale);
  }
  if (t < 8) b2s[t] = b2[t];
  __syncthreads();

  int l = t & 63, w = t >> 6;
  int hp = l & 15, g = l >> 4, hq = hp & 7, qh = hp >> 3;
  int k0 = kcg * 256 + w * 64;
  int kt0 = k0 >> 4;
  int cc = kcg * 4 + w;  // 64-k chunk id (0..31)

  // rd loads + f16 packing (x broadcast pairs); k-row = k0 + r*16 + hp
  unsigned int x2[2][4], y2[2][4];
#pragma unroll
  for (int q = 0; q < 2; ++q) {
    const float* rdb = rd + ((size_t)(b * Q_ + qg * 2 + q) * KL) * 2;
#pragma unroll
    for (int r = 0; r < 4; ++r) {
      float2 p = *(const float2*)(rdb + (k0 + r * 16 + hp) * 2);
      x2[q][r] = pkrtz(p.x, p.x);
      y2[q][r] = pkrtz(p.y, p.y);
    }
  }

  f32x4 acc[4];
#pragma unroll
  for (int r = 0; r < 4; ++r) acc[r] = (f32x4){0.f, 0.f, 0.f, 0.f};

  // swizzled K: lane's 16B for (tile kt0+r, chunk s) at kb[(r*8+s)*64]
  const f16x8* kb = (const f16x8*)kps + ((size_t)(b * 128 + kt0) * 8) * 64 + l;

#pragma unroll
  for (int s = 0; s < 8; ++s) {
    f16x8 kf[4];
#pragma unroll
    for (int r = 0; r < 4; ++r) kf[r] = kb[(r * 8 + s) * 64];
    int pidx = g * 4 + 16 * s;  // half2-pair index
    uintv4 wx = *(const uintv4*)&w1xs[pidx];
    uintv4 wy = *(const uintv4*)&w1ys[pidx];
    uintv4 bp = *(const uintv4*)&b1ps[pidx];
    uintv4 w2r = *(const uintv4*)&w2h[hq][g * 8 + 32 * s];
    UH8 w2q0, w2q1;
#pragma unroll
    for (int m = 0; m < 4; ++m) {
      w2q0.u[m] = (hp < 8) ? w2r[m] : 0u;   // B cols 0-7 = q0 heads
      w2q1.u[m] = (hp < 8) ? 0u : w2r[m];   // B cols 8-15 = q1 heads
    }
    bool sel = (hq == s);
    uintv4 qv = *(const uintv4*)&qs[qh][s * 16 + g * 4];
    UH8 bq;
#pragma unroll
    for (int m = 0; m < 4; ++m) bq.u[m] = sel ? qv[m] : 0u;
#pragma unroll
    for (int r = 0; r < 4; ++r) {
      UH8 az0, az1;
#pragma unroll
      for (int m = 0; m < 4; ++m) {
        az0.u[m] = pk_max0(pk_fma(x2[0][r], wx[m], pk_fma(y2[0][r], wy[m], bp[m])));
        az1.u[m] = pk_max0(pk_fma(x2[1][r], wx[m], pk_fma(y2[1][r], wy[m], bp[m])));
      }
      acc[r] = __builtin_amdgcn_mfma_f32_16x16x32_f16(az0.h, w2q0.h, acc[r], 0, 0, 0);
      acc[r] = __builtin_amdgcn_mfma_f32_16x16x32_f16(az1.h, w2q1.h, acc[r], 0, 0, 0);
      acc[r] = __builtin_amdgcn_mfma_f32_16x16x32_f16(kf[r], bq.h, acc[r], 0, 0, 0);
    }
  }

  // epilogue: lane owns (q = qh, head = hq); 16 k-values in acc
  int qrow = qg * 2 + qh;
  float bhv = b2s[hq];
  float mx = -3.0e38f;
#pragma unroll
  for (int r = 0; r < 4; ++r)
#pragma unroll
    for (int rr = 0; rr < 4; ++rr) {
      acc[r][rr] += bhv;
      mx = fmaxf(mx, acc[r][rr]);
    }
  mx = fmaxf(mx, __shfl_xor(mx, 16));
  mx = fmaxf(mx, __shfl_xor(mx, 32));
  float ss = 0.f;
#pragma unroll
  for (int r = 0; r < 4; ++r)
#pragma unroll
    for (int rr = 0; rr < 4; ++rr) ss += __expf(acc[r][rr] - mx);
  ss += __shfl_xor(ss, 16);
  ss += __shfl_xor(ss, 32);
  if (l < 16)  // g==0 lane per (q,head)
    *(float2*)(stats + (((size_t)(b * H_ + (l & 7)) * Q_ + qg * 2 + (l >> 3)) * 32 + cc) * 2) =
        make_float2(mx, ss);
  unsigned short* ob = lgb + ((size_t)(b * H_ + hq) * Q_ + qrow) * KL + k0;
#pragma unroll
  for (int r = 0; r < 4; ++r) {
    uint2 pk;
    pk.x = pkrtz(acc[r][0], acc[r][1]);
    pk.y = pkrtz(acc[r][2], acc[r][3]);
    *(uint2*)(ob + r * 16 + g * 4) = pk;
  }
}

// ---------- fused softmax + PV, dd-split: block = (bh, qt, dd-half of 16)
__global__ __launch_bounds__(512) void sm_pv(const unsigned short* __restrict__ lgb,
                                             const float* __restrict__ stats,
                                             const unsigned short* __restrict__ vt,
                                             unsigned short* __restrict__ ctxb) {
  int gid = blockIdx.x;
  int dh = gid & 1, qt = (gid >> 1) & 15, bh = gid >> 5;
  int t = threadIdx.x;
  __shared__ float Ms[16], Ss[16];
  __shared__ float pacc[8][16][17];

  {
    int row = t >> 5, cc = t & 31;
    float2 s2 = *(const float2*)(stats +
        (((size_t)bh * Q_ + qt * 16 + row) * 32 + cc) * 2);
    float m = s2.x;
#pragma unroll
    for (int off = 16; off > 0; off >>= 1) m = fmaxf(m, __shfl_xor(m, off));
    float e = s2.y * __expf(s2.x - m);
#pragma unroll
    for (int off = 16; off > 0; off >>= 1) e += __shfl_xor(e, off);
    if (cc == 0) { Ms[row] = m; Ss[row] = 1.0f / e; }
  }
  __syncthreads();

  int l = t & 63, w = t >> 6;
  int qq = l & 15, g = l >> 4;
  float mq = Ms[qq];
  const unsigned short* lr2 =
      lgb + ((size_t)bh * Q_ + qt * 16 + qq) * KL + w * 256 + g * 8;
  const unsigned short* vb =
      vt + ((size_t)bh * HD_ + dh * 16 + qq) * KL + w * 256 + g * 8;
  f32x4 a0 = {0.f, 0.f, 0.f, 0.f};
#pragma unroll
  for (int step = 0; step < 8; ++step) {
    f16x8 raw = *(const f16x8*)(lr2 + step * 32);
    UH8 pa;
#pragma unroll
    for (int mI = 0; mI < 4; ++mI) {
      float p0 = __expf((float)raw[2 * mI] - mq);
      float p1 = __expf((float)raw[2 * mI + 1] - mq);
      pa.u[mI] = pkrtz(p0, p1);
    }
    f16x8 v0 = *(const f16x8*)(vb + step * 32);
    a0 = __builtin_amdgcn_mfma_f32_16x16x32_f16(pa.h, v0, a0, 0, 0, 0);
  }
#pragma unroll
  for (int rr = 0; rr < 4; ++rr) pacc[w][g * 4 + rr][qq] = a0[rr];
  __syncthreads();

  if (t < 256) {
    int qo = t >> 4, dd = t & 15;
    float sum = 0.f;
#pragma unroll
    for (int wv = 0; wv < 8; ++wv) sum += pacc[wv][qo][dd];
    sum *= Ss[qo];
    int b = bh >> 3, h = bh & 7;
    ctxb[((size_t)b * Q_ + qt * 16 + qo) * D_ + h * HD_ + dh * 16 + dd] =
        f16bits(sum);
  }
}

// ---------- out projection: out = ctxb(f16) @ Wo^T + bo (fp32 out)
__global__ __launch_bounds__(256) void gemm_o(const unsigned short* __restrict__ A,
                                              const float* __restrict__ W,
                                              const float* __restrict__ bias,
                                              float* __restrict__ out) {
  int nt = blockIdx.x & 3, mt = blockIdx.x >> 2;
  int t = threadIdx.x, w = t >> 6, l = t & 63;
  int m0 = mt * 16, n0 = nt * 64 + w * 16;
  int r = l & 15, g = l >> 4;
  const unsigned short* arow = A + (size_t)(m0 + r) * D_;
  const float* wrow = W + (size_t)(n0 + r) * D_;
  f32x4 acc = {0.f, 0.f, 0.f, 0.f};
#pragma unroll
  for (int s = 0; s < 8; ++s) {
    int kb = s * 32 + g * 8;
    f16x8 af = *(const f16x8*)(arow + kb);
    f16x8 bf = pack8h(*(const float4*)(wrow + kb), *(const float4*)(wrow + kb + 4));
    acc = __builtin_amdgcn_mfma_f32_16x16x32_f16(af, bf, acc, 0, 0, 0);
  }
  int n = n0 + r;
  float bb = bias[n];
#pragma unroll
  for (int rr = 0; rr < 4; ++rr)
    out[(size_t)(m0 + g * 4 + rr) * D_ + n] = acc[rr] + bb;
}

extern "C" void kernel_launch(void* const* d_in, const int* in_sizes, int n_in,
                              void* d_out, int out_size, void* d_ws, size_t ws_size,
                              hipStream_t stream) {
  const float* ent  = (const float*)d_in[0];
  const float* img  = (const float*)d_in[1];
  const float* rd   = (const float*)d_in[2];
  const float* Wq   = (const float*)d_in[3];
  const float* bq   = (const float*)d_in[4];
  const float* Wkv  = (const float*)d_in[5];
  const float* bkv  = (const float*)d_in[6];
  const float* W1   = (const float*)d_in[7];
  const float* b1   = (const float*)d_in[8];
  const float* W2   = (const float*)d_in[9];
  const float* b2   = (const float*)d_in[10];
  const float* Wo   = (const float*)d_in[11];
  const float* bo   = (const float*)d_in[12];
  float* out = (float*)d_out;

  char* ws = (char*)d_ws;
  float*          qp    = (float*)(ws + 0);                  //   524,288 fp32 [b][q][c]
  unsigned short* kps   = (unsigned short*)(ws + 524288);    // 2,097,152 f16 swizzled K
  unsigned short* vt    = (unsigned short*)(ws + 2621440);   // 2,097,152 f16 [b][h][dd][k]
  unsigned short* lgb   = (unsigned short*)(ws + 4718592);   // 16,777,216 f16 [b][h][q][k]
  float*          stats = (float*)(ws + 21495808);           // 1,048,576 float2 [b][h][q][cc32]
  unsigned short* ctxb  = (unsigned short*)(ws + 22544384);  //   262,144 f16 [b][q][c]

  gemm_qkv<<<dim3(128 + 2048), dim3(256), 0, stream>>>(ent, Wq, bq, qp,
                                                       img, Wkv, bkv, kps, vt);
  logits_cpb<<<dim3(B_ * 128 * 8), dim3(256), 0, stream>>>(qp, kps, rd, W1, b1, W2, b2, lgb, stats);
  sm_pv<<<dim3(B_ * H_ * 16 * 2), dim3(512), 0, stream>>>(lgb, stats, vt, ctxb);
  gemm_o<<<dim3(128), dim3(256), 0, stream>>>(ctxb, Wo, bo, out);
}

// Round 12
// 87.084 us; speedup vs baseline: 1.1586x; 1.1586x over previous
//
#include <hip/hip_runtime.h>
#include <hip/hip_bf16.h>
#include <cstdint>
#include <cstddef>

#define B_  2
#define Q_  256
#define KL  2048
#define D_  256
#define H_  8
#define HD_ 32
#define CH_ 256

typedef _Float16 f16;
typedef __fp16 fp16x2 __attribute__((ext_vector_type(2)));
typedef _Float16 f16x8 __attribute__((ext_vector_type(8)));
typedef unsigned short ushortv4 __attribute__((ext_vector_type(4)));
typedef unsigned int uintv4 __attribute__((ext_vector_type(4)));
typedef float f32x4 __attribute__((ext_vector_type(4)));

union UH  { fp16x2 h; unsigned int u; };
union UH8 { f16x8 h; unsigned int u[4]; };

__device__ __forceinline__ unsigned int pkrtz(float a, float b) {
  UH r; r.h = __builtin_amdgcn_cvt_pkrtz(a, b); return r.u;
}
__device__ __forceinline__ unsigned short f16bits(float a) {
  return (unsigned short)(pkrtz(a, 0.f) & 0xffffu);
}
__device__ __forceinline__ unsigned int pk_fma(unsigned int a, unsigned int b,
                                               unsigned int c) {
  unsigned int d;
  asm("v_pk_fma_f16 %0, %1, %2, %3" : "=v"(d) : "v"(a), "v"(b), "v"(c));
  return d;
}
__device__ __forceinline__ unsigned int pk_max0(unsigned int a) {
  unsigned int d;
  asm("v_pk_max_f16 %0, %1, %2" : "=v"(d) : "v"(a), "v"(0u));
  return d;
}
__device__ __forceinline__ f16x8 pack8h(float4 a0, float4 a1) {
  UH8 u;
  u.u[0] = pkrtz(a0.x, a0.y);
  u.u[1] = pkrtz(a0.z, a0.w);
  u.u[2] = pkrtz(a1.x, a1.y);
  u.u[3] = pkrtz(a1.z, a1.w);
  return u.h;
}

// ---------- merged q + kv projection
// blocks [0,128): q-proj -> qp fp32 [b][q][c]
// blocks [128,2176): kv-proj -> kps swizzled f16 K, vt f16 [b][h][dd][k]
__global__ __launch_bounds__(256) void gemm_qkv(
    const float* __restrict__ ent, const float* __restrict__ Wq,
    const float* __restrict__ bq, float* __restrict__ qp,
    const float* __restrict__ img, const float* __restrict__ Wkv,
    const float* __restrict__ bkv, unsigned short* __restrict__ kps,
    unsigned short* __restrict__ vt) {
  int bid = blockIdx.x;
  int t = threadIdx.x, w = t >> 6, l = t & 63;
  int r = l & 15, g = l >> 4;
  if (bid < 128) {
    int nt = bid & 3, mt = bid >> 2;
    int m0 = mt * 16, n0 = nt * 64 + w * 16;
    const float* arow = ent + (size_t)(m0 + r) * D_;
    const float* wrow = Wq + (size_t)(n0 + r) * D_;
    f32x4 acc = {0.f, 0.f, 0.f, 0.f};
#pragma unroll
    for (int s = 0; s < 8; ++s) {
      int kb = s * 32 + g * 8;
      f16x8 af = pack8h(*(const float4*)(arow + kb), *(const float4*)(arow + kb + 4));
      f16x8 bf = pack8h(*(const float4*)(wrow + kb), *(const float4*)(wrow + kb + 4));
      acc = __builtin_amdgcn_mfma_f32_16x16x32_f16(af, bf, acc, 0, 0, 0);
    }
    int n = n0 + r;
    float bb = bq[n];
#pragma unroll
    for (int rr = 0; rr < 4; ++rr)
      qp[(size_t)(m0 + g * 4 + rr) * D_ + n] = acc[rr] + bb;
  } else {
    int bid2 = bid - 128;
    int nt = bid2 & 7, mt = (bid2 >> 3) & 127, b = bid2 >> 10;
    int m0 = mt * 16, n0 = nt * 64 + w * 16;
    const float* arow = img + (size_t)(b * KL + m0 + r) * D_;
    const float* wrow = Wkv + (size_t)(n0 + r) * D_;
    f32x4 acc = {0.f, 0.f, 0.f, 0.f};
#pragma unroll
    for (int s = 0; s < 8; ++s) {
      int kb = s * 32 + g * 8;
      f16x8 af = pack8h(*(const float4*)(arow + kb), *(const float4*)(arow + kb + 4));
      f16x8 bf = pack8h(*(const float4*)(wrow + kb), *(const float4*)(wrow + kb + 4));
      acc = __builtin_amdgcn_mfma_f32_16x16x32_f16(af, bf, acc, 0, 0, 0);
    }
    int n = n0 + r;
    float bb = bkv[n];
#pragma unroll
    for (int rr = 0; rr < 4; ++rr) acc[rr] += bb;
    if (n < 256) {
      int s2 = n >> 5, gg = (n >> 3) & 3, e = n & 7;
      size_t base = ((size_t)((b * 128 + mt) * 8 + s2) * 64 + gg * 16) * 8 + e;
#pragma unroll
      for (int rr = 0; rr < 4; ++rr)
        kps[base + (size_t)(g * 4 + rr) * 8] = f16bits(acc[rr]);
    } else {
      int c = n - 256, h = c >> 5, dd = c & 31;
      ushortv4 p;
#pragma unroll
      for (int rr = 0; rr < 4; ++rr) p[rr] = f16bits(acc[rr]);
      *(ushortv4*)(vt + ((size_t)(b * H_ + h) * HD_ + dd) * KL + m0 + g * 4) = p;
    }
  }
}

// ---------- logits = QK^T*scale + CPB (f16 MFMA) + per-chunk softmax stats
// block = (b, 2 q-rows, 128 k), 256 threads (4 waves); wave w -> 32-k chunk.
__global__ __launch_bounds__(256, 8) void logits_cpb(
    const float* __restrict__ qp, const unsigned short* __restrict__ kps,
    const float* __restrict__ rd, const float* __restrict__ W1,
    const float* __restrict__ b1, const float* __restrict__ W2,
    const float* __restrict__ b2, unsigned short* __restrict__ lgb,
    float* __restrict__ stats) {
  int gid = blockIdx.x;
  int kcg = gid & 15, qg = (gid >> 4) & 127, b = gid >> 11;
  int t = threadIdx.x;
  __shared__ unsigned int w1xs[128], w1ys[128], b1ps[128];  // half2-packed
  __shared__ unsigned short w2h[H_][264];
  __shared__ unsigned int qs[2][128];  // packed scaled q pairs per q-row
  __shared__ float b2s[H_];
  if (t < 128) {
    float4 wr = *(const float4*)(W1 + 4 * t);  // rows 2t, 2t+1 of W1[256][2]
    w1xs[t] = pkrtz(wr.x, wr.z);
    w1ys[t] = pkrtz(wr.y, wr.w);
    float2 bb = *(const float2*)(b1 + 2 * t);
    b1ps[t] = pkrtz(bb.x, bb.y);
  }
#pragma unroll
  for (int i = 0; i < 2; ++i) {  // all 8 heads (256 thr x 2 = 8h x 64 float4)
    int idx = t + i * 256;
    int h = idx >> 6, c0 = (idx & 63) * 4;
    float4 wv = *(const float4*)(W2 + h * CH_ + c0);
    w2h[h][c0 + 0] = f16bits(wv.x);
    w2h[h][c0 + 1] = f16bits(wv.y);
    w2h[h][c0 + 2] = f16bits(wv.z);
    w2h[h][c0 + 3] = f16bits(wv.w);
  }
  const float scale = 0.17677669529663687f;  // 1/sqrt(32)
  {
    int q = t >> 7, j = t & 127;  // 2q x 128 = 256
    float2 v = *(const float2*)(qp + ((size_t)(b * Q_ + qg * 2 + q) * D_) + 2 * j);
    qs[q][j] = pkrtz(v.x * scale, v.y * scale);
  }
  if (t < 8) b2s[t] = b2[t];
  __syncthreads();

  int l = t & 63, w = t >> 6;
  int hp = l & 15, g = l >> 4, hq = hp & 7;
  int k0 = kcg * 128 + w * 32;
  int kt0 = k0 >> 4;
  int cc = kcg * 4 + w;  // 32-k chunk id (0..63)

  // rd loads + f16 packing (x broadcast pairs)
  unsigned int x2[2][2], y2[2][2];
#pragma unroll
  for (int q = 0; q < 2; ++q) {
    const float* rdb = rd + ((size_t)(b * Q_ + qg * 2 + q) * KL) * 2;
#pragma unroll
    for (int r = 0; r < 2; ++r) {
      float2 p = *(const float2*)(rdb + (k0 + r * 16 + hp) * 2);
      x2[q][r] = pkrtz(p.x, p.x);
      y2[q][r] = pkrtz(p.y, p.y);
    }
  }

  f32x4 acc[2][2];
#pragma unroll
  for (int q = 0; q < 2; ++q)
#pragma unroll
    for (int r = 0; r < 2; ++r) acc[q][r] = (f32x4){0.f, 0.f, 0.f, 0.f};

  // swizzled K: lane's 16B for (tile kt0+r, chunk s) at kb[(r*8+s)*64]
  const f16x8* kb = (const f16x8*)kps + ((size_t)(b * 128 + kt0) * 8) * 64 + l;

#pragma unroll
  for (int s = 0; s < 8; ++s) {
    f16x8 kf[2];
#pragma unroll
    for (int r = 0; r < 2; ++r) kf[r] = kb[(r * 8 + s) * 64];
    int pidx = g * 4 + 16 * s;  // half2-pair index
    uintv4 wx = *(const uintv4*)&w1xs[pidx];
    uintv4 wy = *(const uintv4*)&w1ys[pidx];
    uintv4 bp = *(const uintv4*)&b1ps[pidx];
    f16x8 w2f = *(const f16x8*)&w2h[hq][g * 8 + 32 * s];
    bool sel = (hp == s);
#pragma unroll
    for (int q = 0; q < 2; ++q) {
      uintv4 qv = *(const uintv4*)&qs[q][s * 16 + g * 4];
      UH8 bq;
#pragma unroll
      for (int m = 0; m < 4; ++m) bq.u[m] = sel ? qv[m] : 0u;
#pragma unroll
      for (int r = 0; r < 2; ++r) {
        UH8 az;
#pragma unroll
        for (int m = 0; m < 4; ++m)
          az.u[m] = pk_max0(pk_fma(x2[q][r], wx[m], pk_fma(y2[q][r], wy[m], bp[m])));
        acc[q][r] = __builtin_amdgcn_mfma_f32_16x16x32_f16(az.h, w2f, acc[q][r], 0, 0, 0);
        acc[q][r] = __builtin_amdgcn_mfma_f32_16x16x32_f16(kf[r], bq.h, acc[q][r], 0, 0, 0);
      }
    }
  }

  // per-(q, chunk) epilogue: +b2, wave-internal stats, packed f16 stores
  float bhv = b2s[hq];
#pragma unroll
  for (int q = 0; q < 2; ++q) {
    int qrow = qg * 2 + q;
    float mx = -3.0e38f;
#pragma unroll
    for (int r = 0; r < 2; ++r)
#pragma unroll
      for (int rr = 0; rr < 4; ++rr) {
        acc[q][r][rr] += bhv;
        mx = fmaxf(mx, acc[q][r][rr]);
      }
    mx = fmaxf(mx, __shfl_xor(mx, 16));
    mx = fmaxf(mx, __shfl_xor(mx, 32));
    float ss = 0.f;
#pragma unroll
    for (int r = 0; r < 2; ++r)
#pragma unroll
      for (int rr = 0; rr < 4; ++rr) ss += __expf(acc[q][r][rr] - mx);
    ss += __shfl_xor(ss, 16);
    ss += __shfl_xor(ss, 32);
    if (l < 8)
      *(float2*)(stats + (((size_t)(b * H_ + l) * Q_ + qrow) * 64 + cc) * 2) =
          make_float2(mx, ss);
    if (hp < 8) {
      unsigned short* ob = lgb + ((size_t)(b * H_ + hp) * Q_ + qrow) * KL + k0;
#pragma unroll
      for (int r = 0; r < 2; ++r) {
        uint2 pk;
        pk.x = pkrtz(acc[q][r][0], acc[q][r][1]);
        pk.y = pkrtz(acc[q][r][2], acc[q][r][3]);
        *(uint2*)(ob + r * 16 + g * 4) = pk;
      }
    }
  }
}

// ---------- fused softmax + PV: block = (bh, qt), full 32 dd; 512 threads.
// exp computed once per logit; two MFMAs share the pa fragment.
__global__ __launch_bounds__(512) void sm_pv(const unsigned short* __restrict__ lgb,
                                             const float* __restrict__ stats,
                                             const unsigned short* __restrict__ vt,
                                             unsigned short* __restrict__ ctxb) {
  int gid = blockIdx.x;
  int qt = gid & 15, bh = gid >> 4;
  int t = threadIdx.x;
  __shared__ float Ms[16], Ss[16];
  __shared__ float pacc[8][16][33];

  {
    int row = t >> 5, cc = t & 31;
    const float2* sp = (const float2*)stats + ((size_t)bh * Q_ + qt * 16 + row) * 64;
    float2 s0 = sp[cc], s1 = sp[cc + 32];
    float m = fmaxf(s0.x, s1.x);
#pragma unroll
    for (int off = 16; off > 0; off >>= 1) m = fmaxf(m, __shfl_xor(m, off));
    float e = s0.y * __expf(s0.x - m) + s1.y * __expf(s1.x - m);
#pragma unroll
    for (int off = 16; off > 0; off >>= 1) e += __shfl_xor(e, off);
    if (cc == 0) { Ms[row] = m; Ss[row] = 1.0f / e; }
  }
  __syncthreads();

  int l = t & 63, w = t >> 6;
  int qq = l & 15, g = l >> 4;
  float mq = Ms[qq];
  const unsigned short* lr2 =
      lgb + ((size_t)bh * Q_ + qt * 16 + qq) * KL + w * 256 + g * 8;
  const unsigned short* vb0 =
      vt + ((size_t)bh * HD_ + qq) * KL + w * 256 + g * 8;
  const unsigned short* vb1 = vb0 + (size_t)16 * KL;
  f32x4 a0 = {0.f, 0.f, 0.f, 0.f}, a1 = {0.f, 0.f, 0.f, 0.f};
#pragma unroll
  for (int step = 0; step < 8; ++step) {
    f16x8 raw = *(const f16x8*)(lr2 + step * 32);
    UH8 pa;
#pragma unroll
    for (int mI = 0; mI < 4; ++mI) {
      float p0 = __expf((float)raw[2 * mI] - mq);
      float p1 = __expf((float)raw[2 * mI + 1] - mq);
      pa.u[mI] = pkrtz(p0, p1);
    }
    f16x8 v0 = *(const f16x8*)(vb0 + step * 32);
    f16x8 v1 = *(const f16x8*)(vb1 + step * 32);
    a0 = __builtin_amdgcn_mfma_f32_16x16x32_f16(pa.h, v0, a0, 0, 0, 0);
    a1 = __builtin_amdgcn_mfma_f32_16x16x32_f16(pa.h, v1, a1, 0, 0, 0);
  }
#pragma unroll
  for (int rr = 0; rr < 4; ++rr) {
    pacc[w][g * 4 + rr][qq] = a0[rr];
    pacc[w][g * 4 + rr][qq + 16] = a1[rr];
  }
  __syncthreads();

  {
    int qo = t >> 5, dd = t & 31;
    float sum = 0.f;
#pragma unroll
    for (int wv = 0; wv < 8; ++wv) sum += pacc[wv][qo][dd];
    sum *= Ss[qo];
    int b = bh >> 3, h = bh & 7;
    ctxb[((size_t)b * Q_ + qt * 16 + qo) * D_ + h * HD_ + dd] = f16bits(sum);
  }
}

// ---------- out projection: out = ctxb(f16) @ Wo^T + bo (fp32 out)
__global__ __launch_bounds__(256) void gemm_o(const unsigned short* __restrict__ A,
                                              const float* __restrict__ W,
                                              const float* __restrict__ bias,
                                              float* __restrict__ out) {
  int nt = blockIdx.x & 3, mt = blockIdx.x >> 2;
  int t = threadIdx.x, w = t >> 6, l = t & 63;
  int m0 = mt * 16, n0 = nt * 64 + w * 16;
  int r = l & 15, g = l >> 4;
  const unsigned short* arow = A + (size_t)(m0 + r) * D_;
  const float* wrow = W + (size_t)(n0 + r) * D_;
  f32x4 acc = {0.f, 0.f, 0.f, 0.f};
#pragma unroll
  for (int s = 0; s < 8; ++s) {
    int kb = s * 32 + g * 8;
    f16x8 af = *(const f16x8*)(arow + kb);
    f16x8 bf = pack8h(*(const float4*)(wrow + kb), *(const float4*)(wrow + kb + 4));
    acc = __builtin_amdgcn_mfma_f32_16x16x32_f16(af, bf, acc, 0, 0, 0);
  }
  int n = n0 + r;
  float bb = bias[n];
#pragma unroll
  for (int rr = 0; rr < 4; ++rr)
    out[(size_t)(m0 + g * 4 + rr) * D_ + n] = acc[rr] + bb;
}

extern "C" void kernel_launch(void* const* d_in, const int* in_sizes, int n_in,
                              void* d_out, int out_size, void* d_ws, size_t ws_size,
                              hipStream_t stream) {
  const float* ent  = (const float*)d_in[0];
  const float* img  = (const float*)d_in[1];
  const float* rd   = (const float*)d_in[2];
  const float* Wq   = (const float*)d_in[3];
  const float* bq   = (const float*)d_in[4];
  const float* Wkv  = (const float*)d_in[5];
  const float* bkv  = (const float*)d_in[6];
  const float* W1   = (const float*)d_in[7];
  const float* b1   = (const float*)d_in[8];
  const float* W2   = (const float*)d_in[9];
  const float* b2   = (const float*)d_in[10];
  const float* Wo   = (const float*)d_in[11];
  const float* bo   = (const float*)d_in[12];
  float* out = (float*)d_out;

  char* ws = (char*)d_ws;
  float*          qp    = (float*)(ws + 0);                  //   524,288 fp32 [b][q][c]
  unsigned short* kps   = (unsigned short*)(ws + 524288);    // 2,097,152 f16 swizzled K
  unsigned short* vt    = (unsigned short*)(ws + 2621440);   // 2,097,152 f16 [b][h][dd][k]
  unsigned short* lgb   = (unsigned short*)(ws + 4718592);   // 16,777,216 f16 [b][h][q][k]
  float*          stats = (float*)(ws + 21495808);           // 2,097,152 float2 [b][h][q][cc64]
  unsigned short* ctxb  = (unsigned short*)(ws + 23592960);  //   262,144 f16 [b][q][c]

  gemm_qkv<<<dim3(128 + 2048), dim3(256), 0, stream>>>(ent, Wq, bq, qp,
                                                       img, Wkv, bkv, kps, vt);
  logits_cpb<<<dim3(B_ * 128 * 16), dim3(256), 0, stream>>>(qp, kps, rd, W1, b1, W2, b2, lgb, stats);
  sm_pv<<<dim3(B_ * H_ * 16), dim3(512), 0, stream>>>(lgb, stats, vt, ctxb);
  gemm_o<<<dim3(128), dim3(256), 0, stream>>>(ctxb, Wo, bo, out);
}

// Round 13
// 60.586 us; speedup vs baseline: 1.6653x; 1.4374x over previous
//
#include <hip/hip_runtime.h>
#include <hip/hip_bf16.h>
#include <cstdint>
#include <cstddef>

#define B_  2
#define Q_  256
#define KL  2048
#define D_  256
#define H_  8
#define HD_ 32
#define CH_ 256

typedef _Float16 f16;
typedef __fp16 fp16x2 __attribute__((ext_vector_type(2)));
typedef _Float16 f16x8 __attribute__((ext_vector_type(8)));
typedef unsigned short ushortv4 __attribute__((ext_vector_type(4)));
typedef unsigned int uintv4 __attribute__((ext_vector_type(4)));
typedef float f32x4 __attribute__((ext_vector_type(4)));

union UH  { fp16x2 h; unsigned int u; };
union UH8 { f16x8 h; unsigned int u[4]; };

__device__ __forceinline__ unsigned int pkrtz(float a, float b) {
  UH r; r.h = __builtin_amdgcn_cvt_pkrtz(a, b); return r.u;
}
__device__ __forceinline__ unsigned short f16bits(float a) {
  return (unsigned short)(pkrtz(a, 0.f) & 0xffffu);
}
__device__ __forceinline__ unsigned int pk_fma(unsigned int a, unsigned int b,
                                               unsigned int c) {
  unsigned int d;
  asm("v_pk_fma_f16 %0, %1, %2, %3" : "=v"(d) : "v"(a), "v"(b), "v"(c));
  return d;
}
__device__ __forceinline__ unsigned int pk_max0(unsigned int a) {
  unsigned int d;
  asm("v_pk_max_f16 %0, %1, %2" : "=v"(d) : "v"(a), "v"(0u));
  return d;
}

// ---------- prep: convert fp32 row-major sources to f16 MFMA-fragment layout
// frag array: ((f16x8*)dst)[(tile*8 + s)*64 + lane] =
//   src[tile*16 + (lane&15)][s*32 + (lane>>4)*8 .. +8]
// tiles: [0,32) ent | [32,288) img | [288,304) Wq | [304,336) Wkv | [336,352) Wo
__global__ __launch_bounds__(512) void prep(
    const float* __restrict__ ent, const float* __restrict__ img,
    const float* __restrict__ Wq, const float* __restrict__ Wkv,
    const float* __restrict__ Wo,
    unsigned short* __restrict__ entS, unsigned short* __restrict__ imgS,
    unsigned short* __restrict__ WqS, unsigned short* __restrict__ WkvS,
    unsigned short* __restrict__ WoS) {
  int bid = blockIdx.x, t = threadIdx.x;
  const float* src;
  unsigned short* dst;
  if (bid < 32)       { src = ent + (size_t)bid * 16 * D_;          dst = entS + (size_t)bid * 4096; }
  else if (bid < 288) { int k = bid - 32;  src = img + (size_t)k * 16 * D_; dst = imgS + (size_t)k * 4096; }
  else if (bid < 304) { int k = bid - 288; src = Wq  + (size_t)k * 16 * D_; dst = WqS  + (size_t)k * 4096; }
  else if (bid < 336) { int k = bid - 304; src = Wkv + (size_t)k * 16 * D_; dst = WkvS + (size_t)k * 4096; }
  else                { int k = bid - 336; src = Wo  + (size_t)k * 16 * D_; dst = WoS  + (size_t)k * 4096; }
  __shared__ float rows[16][257];
  {
    int rr = t >> 5, c0 = (t & 31) * 8;  // 16 rows x 32 chunks of 8 floats
    float4 a = *(const float4*)(src + rr * D_ + c0);
    float4 b = *(const float4*)(src + rr * D_ + c0 + 4);
    rows[rr][c0 + 0] = a.x; rows[rr][c0 + 1] = a.y;
    rows[rr][c0 + 2] = a.z; rows[rr][c0 + 3] = a.w;
    rows[rr][c0 + 4] = b.x; rows[rr][c0 + 5] = b.y;
    rows[rr][c0 + 6] = b.z; rows[rr][c0 + 7] = b.w;
  }
  __syncthreads();
  int s = t >> 6, l = t & 63, r = l & 15, g = l >> 4;
  const float* rp = &rows[r][s * 32 + g * 8];
  UH8 u;
#pragma unroll
  for (int m = 0; m < 4; ++m) u.u[m] = pkrtz(rp[2 * m], rp[2 * m + 1]);
  ((f16x8*)dst)[s * 64 + l] = u.h;
}

// ---------- fused q + kv projection from fragment-swizzled inputs
// blocks [0,64): q-proj (qp fp32); [64,1088): kv-proj (kps swizzled K, vt)
__global__ __launch_bounds__(256) void gemm2(
    const unsigned short* __restrict__ entS, const unsigned short* __restrict__ WqS,
    const float* __restrict__ bq, float* __restrict__ qp,
    const unsigned short* __restrict__ imgS, const unsigned short* __restrict__ WkvS,
    const float* __restrict__ bkv, unsigned short* __restrict__ kps,
    unsigned short* __restrict__ vt) {
  int bid = blockIdx.x;
  int t = threadIdx.x, w = t >> 6, l = t & 63;
  int r = l & 15, g = l >> 4;
  if (bid < 64) {
    int nt = bid & 3, mg = bid >> 2;  // 32 rows per mg
    const f16x8* A = (const f16x8*)entS;
    const f16x8* Bf = (const f16x8*)WqS;
    int tA0 = mg * 2, tB = nt * 4 + w;
    f16x8 a0[8], a1[8], bf[8];
#pragma unroll
    for (int s = 0; s < 8; ++s) {
      a0[s] = A[(tA0 * 8 + s) * 64 + l];
      a1[s] = A[((tA0 + 1) * 8 + s) * 64 + l];
      bf[s] = Bf[(tB * 8 + s) * 64 + l];
    }
    f32x4 acc0 = {0.f, 0.f, 0.f, 0.f}, acc1 = {0.f, 0.f, 0.f, 0.f};
#pragma unroll
    for (int s = 0; s < 8; ++s) {
      acc0 = __builtin_amdgcn_mfma_f32_16x16x32_f16(a0[s], bf[s], acc0, 0, 0, 0);
      acc1 = __builtin_amdgcn_mfma_f32_16x16x32_f16(a1[s], bf[s], acc1, 0, 0, 0);
    }
    int n = nt * 64 + w * 16 + r;
    float bb = bq[n];
    int m0 = mg * 32;
#pragma unroll
    for (int rr = 0; rr < 4; ++rr) {
      qp[(size_t)(m0 + g * 4 + rr) * D_ + n] = acc0[rr] + bb;
      qp[(size_t)(m0 + 16 + g * 4 + rr) * D_ + n] = acc1[rr] + bb;
    }
  } else {
    int bid2 = bid - 64;
    int nt = bid2 & 7, mg = (bid2 >> 3) & 63, b = bid2 >> 9;
    const f16x8* A = (const f16x8*)imgS;
    const f16x8* Bf = (const f16x8*)WkvS;
    int tA0 = b * 128 + mg * 2, tB = nt * 4 + w;
    f16x8 a0[8], a1[8], bf[8];
#pragma unroll
    for (int s = 0; s < 8; ++s) {
      a0[s] = A[(tA0 * 8 + s) * 64 + l];
      a1[s] = A[((tA0 + 1) * 8 + s) * 64 + l];
      bf[s] = Bf[(tB * 8 + s) * 64 + l];
    }
    f32x4 acc0 = {0.f, 0.f, 0.f, 0.f}, acc1 = {0.f, 0.f, 0.f, 0.f};
#pragma unroll
    for (int s = 0; s < 8; ++s) {
      acc0 = __builtin_amdgcn_mfma_f32_16x16x32_f16(a0[s], bf[s], acc0, 0, 0, 0);
      acc1 = __builtin_amdgcn_mfma_f32_16x16x32_f16(a1[s], bf[s], acc1, 0, 0, 0);
    }
    int n = nt * 64 + w * 16 + r;
    float bb = bkv[n];
#pragma unroll
    for (int mi = 0; mi < 2; ++mi) {
      f32x4 ac = (mi == 0) ? acc0 : acc1;
      int mt = mg * 2 + mi;
      if (n < 256) {
        int s2 = n >> 5, gg = (n >> 3) & 3, e = n & 7;
        size_t base = ((size_t)((b * 128 + mt) * 8 + s2) * 64 + gg * 16) * 8 + e;
#pragma unroll
        for (int rr = 0; rr < 4; ++rr)
          kps[base + (size_t)(g * 4 + rr) * 8] = f16bits(ac[rr] + bb);
      } else {
        int c = n - 256, h = c >> 5, dd = c & 31;
        ushortv4 p;
#pragma unroll
        for (int rr = 0; rr < 4; ++rr) p[rr] = f16bits(ac[rr] + bb);
        *(ushortv4*)(vt + ((size_t)(b * H_ + h) * HD_ + dd) * KL + mt * 16 + g * 4) = p;
      }
    }
  }
}

// ---------- logits = QK^T*scale + CPB (f16 MFMA) + per-chunk softmax stats
// block = (b, 2 q-rows, 128 k), 256 threads (4 waves); wave w -> 32-k chunk.
__global__ __launch_bounds__(256, 8) void logits_cpb(
    const float* __restrict__ qp, const unsigned short* __restrict__ kps,
    const float* __restrict__ rd, const float* __restrict__ W1,
    const float* __restrict__ b1, const float* __restrict__ W2,
    const float* __restrict__ b2, unsigned short* __restrict__ lgb,
    float* __restrict__ stats) {
  int gid = blockIdx.x;
  int kcg = gid & 15, qg = (gid >> 4) & 127, b = gid >> 11;
  int t = threadIdx.x;
  __shared__ unsigned int w1xs[128], w1ys[128], b1ps[128];  // half2-packed
  __shared__ unsigned short w2h[H_][264];
  __shared__ unsigned int qs[2][128];  // packed scaled q pairs per q-row
  __shared__ float b2s[H_];
  if (t < 128) {
    float4 wr = *(const float4*)(W1 + 4 * t);  // rows 2t, 2t+1 of W1[256][2]
    w1xs[t] = pkrtz(wr.x, wr.z);
    w1ys[t] = pkrtz(wr.y, wr.w);
    float2 bb = *(const float2*)(b1 + 2 * t);
    b1ps[t] = pkrtz(bb.x, bb.y);
  }
#pragma unroll
  for (int i = 0; i < 2; ++i) {  // all 8 heads (256 thr x 2 = 8h x 64 float4)
    int idx = t + i * 256;
    int h = idx >> 6, c0 = (idx & 63) * 4;
    float4 wv = *(const float4*)(W2 + h * CH_ + c0);
    w2h[h][c0 + 0] = f16bits(wv.x);
    w2h[h][c0 + 1] = f16bits(wv.y);
    w2h[h][c0 + 2] = f16bits(wv.z);
    w2h[h][c0 + 3] = f16bits(wv.w);
  }
  const float scale = 0.17677669529663687f;  // 1/sqrt(32)
  {
    int q = t >> 7, j = t & 127;  // 2q x 128 = 256
    float2 v = *(const float2*)(qp + ((size_t)(b * Q_ + qg * 2 + q) * D_) + 2 * j);
    qs[q][j] = pkrtz(v.x * scale, v.y * scale);
  }
  if (t < 8) b2s[t] = b2[t];
  __syncthreads();

  int l = t & 63, w = t >> 6;
  int hp = l & 15, g = l >> 4, hq = hp & 7;
  int k0 = kcg * 128 + w * 32;
  int kt0 = k0 >> 4;
  int cc = kcg * 4 + w;  // 32-k chunk id (0..63)

  // rd loads + f16 packing (x broadcast pairs)
  unsigned int x2[2][2], y2[2][2];
#pragma unroll
  for (int q = 0; q < 2; ++q) {
    const float* rdb = rd + ((size_t)(b * Q_ + qg * 2 + q) * KL) * 2;
#pragma unroll
    for (int r = 0; r < 2; ++r) {
      float2 p = *(const float2*)(rdb + (k0 + r * 16 + hp) * 2);
      x2[q][r] = pkrtz(p.x, p.x);
      y2[q][r] = pkrtz(p.y, p.y);
    }
  }

  f32x4 acc[2][2];
#pragma unroll
  for (int q = 0; q < 2; ++q)
#pragma unroll
    for (int r = 0; r < 2; ++r) acc[q][r] = (f32x4){0.f, 0.f, 0.f, 0.f};

  // swizzled K: lane's 16B for (tile kt0+r, chunk s) at kb[(r*8+s)*64]
  const f16x8* kb = (const f16x8*)kps + ((size_t)(b * 128 + kt0) * 8) * 64 + l;

#pragma unroll
  for (int s = 0; s < 8; ++s) {
    f16x8 kf[2];
#pragma unroll
    for (int r = 0; r < 2; ++r) kf[r] = kb[(r * 8 + s) * 64];
    int pidx = g * 4 + 16 * s;  // half2-pair index
    uintv4 wx = *(const uintv4*)&w1xs[pidx];
    uintv4 wy = *(const uintv4*)&w1ys[pidx];
    uintv4 bp = *(const uintv4*)&b1ps[pidx];
    f16x8 w2f = *(const f16x8*)&w2h[hq][g * 8 + 32 * s];
    bool sel = (hp == s);
#pragma unroll
    for (int q = 0; q < 2; ++q) {
      uintv4 qv = *(const uintv4*)&qs[q][s * 16 + g * 4];
      UH8 bq;
#pragma unroll
      for (int m = 0; m < 4; ++m) bq.u[m] = sel ? qv[m] : 0u;
#pragma unroll
      for (int r = 0; r < 2; ++r) {
        UH8 az;
#pragma unroll
        for (int m = 0; m < 4; ++m)
          az.u[m] = pk_max0(pk_fma(x2[q][r], wx[m], pk_fma(y2[q][r], wy[m], bp[m])));
        acc[q][r] = __builtin_amdgcn_mfma_f32_16x16x32_f16(az.h, w2f, acc[q][r], 0, 0, 0);
        acc[q][r] = __builtin_amdgcn_mfma_f32_16x16x32_f16(kf[r], bq.h, acc[q][r], 0, 0, 0);
      }
    }
  }

  // per-(q, chunk) epilogue: +b2, wave-internal stats, packed f16 stores
  float bhv = b2s[hq];
#pragma unroll
  for (int q = 0; q < 2; ++q) {
    int qrow = qg * 2 + q;
    float mx = -3.0e38f;
#pragma unroll
    for (int r = 0; r < 2; ++r)
#pragma unroll
      for (int rr = 0; rr < 4; ++rr) {
        acc[q][r][rr] += bhv;
        mx = fmaxf(mx, acc[q][r][rr]);
      }
    mx = fmaxf(mx, __shfl_xor(mx, 16));
    mx = fmaxf(mx, __shfl_xor(mx, 32));
    float ss = 0.f;
#pragma unroll
    for (int r = 0; r < 2; ++r)
#pragma unroll
      for (int rr = 0; rr < 4; ++rr) ss += __expf(acc[q][r][rr] - mx);
    ss += __shfl_xor(ss, 16);
    ss += __shfl_xor(ss, 32);
    if (l < 8)
      *(float2*)(stats + (((size_t)(b * H_ + l) * Q_ + qrow) * 64 + cc) * 2) =
          make_float2(mx, ss);
    if (hp < 8) {
      unsigned short* ob = lgb + ((size_t)(b * H_ + hp) * Q_ + qrow) * KL + k0;
#pragma unroll
      for (int r = 0; r < 2; ++r) {
        uint2 pk;
        pk.x = pkrtz(acc[q][r][0], acc[q][r][1]);
        pk.y = pkrtz(acc[q][r][2], acc[q][r][3]);
        *(uint2*)(ob + r * 16 + g * 4) = pk;
      }
    }
  }
}

// ---------- fused softmax + PV: block = (bh, qt), full 32 dd; 512 threads.
__global__ __launch_bounds__(512) void sm_pv(const unsigned short* __restrict__ lgb,
                                             const float* __restrict__ stats,
                                             const unsigned short* __restrict__ vt,
                                             unsigned short* __restrict__ ctxb) {
  int gid = blockIdx.x;
  int qt = gid & 15, bh = gid >> 4;
  int t = threadIdx.x;
  __shared__ float Ms[16], Ss[16];
  __shared__ float pacc[8][16][33];

  {
    int row = t >> 5, cc = t & 31;
    const float2* sp = (const float2*)stats + ((size_t)bh * Q_ + qt * 16 + row) * 64;
    float2 s0 = sp[cc], s1 = sp[cc + 32];
    float m = fmaxf(s0.x, s1.x);
#pragma unroll
    for (int off = 16; off > 0; off >>= 1) m = fmaxf(m, __shfl_xor(m, off));
    float e = s0.y * __expf(s0.x - m) + s1.y * __expf(s1.x - m);
#pragma unroll
    for (int off = 16; off > 0; off >>= 1) e += __shfl_xor(e, off);
    if (cc == 0) { Ms[row] = m; Ss[row] = 1.0f / e; }
  }
  __syncthreads();

  int l = t & 63, w = t >> 6;
  int qq = l & 15, g = l >> 4;
  float mq = Ms[qq];
  const unsigned short* lr2 =
      lgb + ((size_t)bh * Q_ + qt * 16 + qq) * KL + w * 256 + g * 8;
  const unsigned short* vb0 =
      vt + ((size_t)bh * HD_ + qq) * KL + w * 256 + g * 8;
  const unsigned short* vb1 = vb0 + (size_t)16 * KL;
  f32x4 a0 = {0.f, 0.f, 0.f, 0.f}, a1 = {0.f, 0.f, 0.f, 0.f};
#pragma unroll
  for (int step = 0; step < 8; ++step) {
    f16x8 raw = *(const f16x8*)(lr2 + step * 32);
    UH8 pa;
#pragma unroll
    for (int mI = 0; mI < 4; ++mI) {
      float p0 = __expf((float)raw[2 * mI] - mq);
      float p1 = __expf((float)raw[2 * mI + 1] - mq);
      pa.u[mI] = pkrtz(p0, p1);
    }
    f16x8 v0 = *(const f16x8*)(vb0 + step * 32);
    f16x8 v1 = *(const f16x8*)(vb1 + step * 32);
    a0 = __builtin_amdgcn_mfma_f32_16x16x32_f16(pa.h, v0, a0, 0, 0, 0);
    a1 = __builtin_amdgcn_mfma_f32_16x16x32_f16(pa.h, v1, a1, 0, 0, 0);
  }
#pragma unroll
  for (int rr = 0; rr < 4; ++rr) {
    pacc[w][g * 4 + rr][qq] = a0[rr];
    pacc[w][g * 4 + rr][qq + 16] = a1[rr];
  }
  __syncthreads();

  {
    int qo = t >> 5, dd = t & 31;
    float sum = 0.f;
#pragma unroll
    for (int wv = 0; wv < 8; ++wv) sum += pacc[wv][qo][dd];
    sum *= Ss[qo];
    int b = bh >> 3, h = bh & 7;
    ctxb[((size_t)b * Q_ + qt * 16 + qo) * D_ + h * HD_ + dd] = f16bits(sum);
  }
}

// ---------- out projection: out = ctxb(f16) @ Wo^T + bo (fp32 out)
__global__ __launch_bounds__(256) void gemm_o(const unsigned short* __restrict__ A,
                                              const unsigned short* __restrict__ WoS,
                                              const float* __restrict__ bias,
                                              float* __restrict__ out) {
  int nt = blockIdx.x & 3, mt = blockIdx.x >> 2;
  int t = threadIdx.x, w = t >> 6, l = t & 63;
  int m0 = mt * 16;
  int r = l & 15, g = l >> 4;
  const unsigned short* arow = A + (size_t)(m0 + r) * D_;
  int tB = nt * 4 + w;
  f16x8 af[8], bf[8];
#pragma unroll
  for (int s = 0; s < 8; ++s) {
    af[s] = *(const f16x8*)(arow + s * 32 + g * 8);
    bf[s] = ((const f16x8*)WoS)[(tB * 8 + s) * 64 + l];
  }
  f32x4 acc = {0.f, 0.f, 0.f, 0.f};
#pragma unroll
  for (int s = 0; s < 8; ++s)
    acc = __builtin_amdgcn_mfma_f32_16x16x32_f16(af[s], bf[s], acc, 0, 0, 0);
  int n = nt * 64 + w * 16 + r;
  float bb = bias[n];
#pragma unroll
  for (int rr = 0; rr < 4; ++rr)
    out[(size_t)(m0 + g * 4 + rr) * D_ + n] = acc[rr] + bb;
}

extern "C" void kernel_launch(void* const* d_in, const int* in_sizes, int n_in,
                              void* d_out, int out_size, void* d_ws, size_t ws_size,
                              hipStream_t stream) {
  const float* ent  = (const float*)d_in[0];
  const float* img  = (const float*)d_in[1];
  const float* rd   = (const float*)d_in[2];
  const float* Wq   = (const float*)d_in[3];
  const float* bq   = (const float*)d_in[4];
  const float* Wkv  = (const float*)d_in[5];
  const float* bkv  = (const float*)d_in[6];
  const float* W1   = (const float*)d_in[7];
  const float* b1   = (const float*)d_in[8];
  const float* W2   = (const float*)d_in[9];
  const float* b2   = (const float*)d_in[10];
  const float* Wo   = (const float*)d_in[11];
  const float* bo   = (const float*)d_in[12];
  float* out = (float*)d_out;

  char* ws = (char*)d_ws;
  float*          qp    = (float*)(ws + 0);                  //   524,288 fp32 [b][q][c]
  unsigned short* kps   = (unsigned short*)(ws + 524288);    // 2,097,152 f16 swizzled K
  unsigned short* vt    = (unsigned short*)(ws + 2621440);   // 2,097,152 f16 [b][h][dd][k]
  unsigned short* lgb   = (unsigned short*)(ws + 4718592);   // 16,777,216 f16 [b][h][q][k]
  float*          stats = (float*)(ws + 21495808);           // 2,097,152 float2 [b][h][q][cc64]
  unsigned short* ctxb  = (unsigned short*)(ws + 23592960);  //   262,144 f16 [b][q][c]
  unsigned short* entS  = (unsigned short*)(ws + 23855104);  //   262,144 f16 frag
  unsigned short* imgS  = (unsigned short*)(ws + 24117248);  // 2,097,152 f16 frag
  unsigned short* WqS   = (unsigned short*)(ws + 26214400);  //   131,072 f16 frag
  unsigned short* WkvS  = (unsigned short*)(ws + 26345472);  //   262,144 f16 frag
  unsigned short* WoS   = (unsigned short*)(ws + 26607616);  //   131,072 f16 frag

  prep<<<dim3(352), dim3(512), 0, stream>>>(ent, img, Wq, Wkv, Wo,
                                            entS, imgS, WqS, WkvS, WoS);
  gemm2<<<dim3(64 + 1024), dim3(256), 0, stream>>>(entS, WqS, bq, qp,
                                                   imgS, WkvS, bkv, kps, vt);
  logits_cpb<<<dim3(B_ * 128 * 16), dim3(256), 0, stream>>>(qp, kps, rd, W1, b1, W2, b2, lgb, stats);
  sm_pv<<<dim3(B_ * H_ * 16), dim3(512), 0, stream>>>(lgb, stats, vt, ctxb);
  gemm_o<<<dim3(128), dim3(256), 0, stream>>>(ctxb, WoS, bo, out);
}